// Round 11
// baseline (195.306 us; speedup 1.0000x reference)
//
#include <hip/hip_runtime.h>
#include <hip/hip_bf16.h>

#define HIDDEN 1024
#define NH 16
#define BATCH 2
#define SEQ 2048

typedef __attribute__((ext_vector_type(8))) short bf16x8;
typedef __attribute__((ext_vector_type(4))) float f32x4;

__device__ __forceinline__ ushort f2bf(float f) {
    __hip_bfloat16 h = __float2bfloat16(f);
    return *reinterpret_cast<ushort*>(&h);
}
__device__ __forceinline__ float fexp2(float x) {
#if __has_builtin(__builtin_amdgcn_exp2f)
    return __builtin_amdgcn_exp2f(x);
#else
    return exp2f(x);
#endif
}
// pack trunc-bf16(a) low, trunc-bf16(b) high (1 v_perm)
__device__ __forceinline__ uint pack_bf_trunc(float a, float b) {
    return __builtin_amdgcn_perm(__float_as_uint(b), __float_as_uint(a), 0x07060302u);
}

// async global->LDS, 16B per lane
__device__ __forceinline__ void async_copy16(const ushort* g, ushort* l) {
    __builtin_amdgcn_global_load_lds((const __attribute__((address_space(1))) void*)g,
                                     (__attribute__((address_space(3))) void*)l,
                                     16, 0, 0);
}

// ---------------------------------------------------------------------------
// Fused prep: [0,4096) x->bf16 | [4096,7168) Wqkv transpose | [7168,8192) Wo transpose
// ---------------------------------------------------------------------------
__global__ void prep_kernel(const float* __restrict__ x,
                            const float* __restrict__ Wqkv,
                            const float* __restrict__ Wo,
                            ushort* __restrict__ xb,
                            ushort* __restrict__ Wt,
                            ushort* __restrict__ WoT)
{
    __shared__ float t[32][33];
    const int bid = blockIdx.x;
    const int tid = threadIdx.x;

    if (bid < 4096) {
        int i = (bid * 256 + tid) * 4;
        float4 v = *(const float4*)(x + i);
        ushort4 w;
        w.x = f2bf(v.x); w.y = f2bf(v.y); w.z = f2bf(v.z); w.w = f2bf(v.w);
        *(ushort4*)(xb + i) = w;
        return;
    }
    const int r = tid >> 3;
    const int c = (tid & 7) * 4;
    if (bid < 7168) {
        int tt = bid - 4096;
        int k0 = (tt & 31) * 32;
        int n0 = (tt >> 5) * 32;
        const int N = 3 * HIDDEN, K = HIDDEN;
        float4 v = *(const float4*)(Wqkv + (size_t)(k0 + r) * N + n0 + c);
        t[r][c] = v.x; t[r][c + 1] = v.y; t[r][c + 2] = v.z; t[r][c + 3] = v.w;
        __syncthreads();
        ushort4 w;
        w.x = f2bf(t[c + 0][r]); w.y = f2bf(t[c + 1][r]);
        w.z = f2bf(t[c + 2][r]); w.w = f2bf(t[c + 3][r]);
        *(ushort4*)(Wt + (size_t)(n0 + r) * K + k0 + c) = w;
    } else {
        int tt = bid - 7168;
        int k0 = (tt & 31) * 32;
        int n0 = (tt >> 5) * 32;
        const int N = HIDDEN, K = HIDDEN;
        float4 v = *(const float4*)(Wo + (size_t)(k0 + r) * N + n0 + c);
        t[r][c] = v.x; t[r][c + 1] = v.y; t[r][c + 2] = v.z; t[r][c + 3] = v.w;
        __syncthreads();
        ushort4 w;
        w.x = f2bf(t[c + 0][r]); w.y = f2bf(t[c + 1][r]);
        w.z = f2bf(t[c + 2][r]); w.w = f2bf(t[c + 3][r]);
        *(ushort4*)(WoT + (size_t)(n0 + r) * K + k0 + c) = w;
    }
}

// ---------------------------------------------------------------------------
// bf16 MFMA GEMM1: qkv = x @ Wqkv^T + bias -> bf16. Q cols scaled by qscale
// (0.125*log2e -> softmax via exp2). When vt_mode, V cols (>=2048) go
// transposed + Pi-permuted into vtg[b][h][d][s'] (fused transpose_v).
// ---------------------------------------------------------------------------
__global__ __launch_bounds__(256, 3)
void gemm_mfma_bf16_kernel(const ushort* __restrict__ A,
                           const ushort* __restrict__ Bt,
                           const float* __restrict__ bias,
                           ushort* __restrict__ C, int N,
                           int qscale_cols, float qscale,
                           ushort* __restrict__ vtg, int vt_mode)
{
    constexpr int K = 1024;
    __shared__ ushort As[128 * 64];
    __shared__ ushort Bs[128 * 64];

    const int tid  = threadIdx.x;
    const int wave = tid >> 6;
    const int lane = tid & 63;
    const int l16  = lane & 15;
    const int quad = lane >> 4;
    const int wm = wave & 1, wn = wave >> 1;

    const int bm = blockIdx.y * 128;
    const int bn = blockIdx.x * 128;

    const int srow = lane >> 3;
    const int lblk = (lane & 7) ^ srow;
    const ushort* Ag = A  + (size_t)(bm + wave * 32 + srow) * K + lblk * 8;
    const ushort* Bg = Bt + (size_t)(bn + wave * 32 + srow) * K + lblk * 8;
    ushort* Asl = As + wave * 32 * 64;
    ushort* Bsl = Bs + wave * 32 * 64;

    f32x4 acc[4][4];
    #pragma unroll
    for (int i = 0; i < 4; i++)
        #pragma unroll
        for (int j = 0; j < 4; j++) acc[i][j] = (f32x4){0.f, 0.f, 0.f, 0.f};

    for (int k0 = 0; k0 < K; k0 += 64) {
        __syncthreads();
        #pragma unroll
        for (int t = 0; t < 4; t++) {
            async_copy16(Ag + (size_t)t * 8 * K + k0, Asl + t * 8 * 64);
            async_copy16(Bg + (size_t)t * 8 * K + k0, Bsl + t * 8 * 64);
        }
        __syncthreads();

        #pragma unroll
        for (int s = 0; s < 2; s++) {
            bf16x8 af[4], bfr[4];
            #pragma unroll
            for (int i = 0; i < 4; i++) {
                int m = wm * 64 + i * 16 + l16;
                int n = wn * 64 + i * 16 + l16;
                af[i]  = *(const bf16x8*)&As[m * 64 + (((s * 4 + quad) ^ (m & 7)) << 3)];
                bfr[i] = *(const bf16x8*)&Bs[n * 64 + (((s * 4 + quad) ^ (n & 7)) << 3)];
            }
            #pragma unroll
            for (int i = 0; i < 4; i++)
                #pragma unroll
                for (int j = 0; j < 4; j++)
                    acc[i][j] = __builtin_amdgcn_mfma_f32_16x16x32_bf16(af[i], bfr[j], acc[i][j], 0, 0, 0);
        }
    }

    #pragma unroll
    for (int j = 0; j < 4; j++) {
        int col = bn + wn * 64 + j * 16 + l16;
        float bv = bias[col];
        if (vt_mode && col >= 2048) {
            // V -> vtg transposed + Pi: s64 = i*16+quad*4+r; Pi(s64)=(quad*4+r)*4+i
            int dfull = col - 2048;
            int hh = dfull >> 6, dd = dfull & 63;
            int bb = bm >> 11;
            int sb = ((bm & 2047) + wm * 64) >> 6;
            ushort tmp[16];
            #pragma unroll
            for (int i = 0; i < 4; i++)
                #pragma unroll
                for (int r = 0; r < 4; r++)
                    tmp[r * 4 + i] = f2bf(acc[i][j][r] + bv);
            ushort* dst = vtg + ((size_t)((bb * NH + hh) * 64 + dd)) * SEQ
                          + sb * 64 + quad * 16;
            *(uint4*)dst = *(const uint4*)tmp;
            *(uint4*)(dst + 8) = *(const uint4*)(tmp + 8);
        } else {
            float s = (col < qscale_cols) ? qscale : 1.0f;
            #pragma unroll
            for (int i = 0; i < 4; i++) {
                int row0 = bm + wm * 64 + i * 16 + quad * 4;
                #pragma unroll
                for (int r = 0; r < 4; r++)
                    C[(size_t)(row0 + r) * N + col] = f2bf((acc[i][j][r] + bv) * s);
            }
        }
    }
}

// ---------------------------------------------------------------------------
// Output projection, single-pass bf16 MFMA: C[4096][1024]f32 = attn @ WoT^T + bo.
// ---------------------------------------------------------------------------
__global__ __launch_bounds__(256, 4)
void gemm_out_kernel(const ushort* __restrict__ A,
                     const ushort* __restrict__ Bt,
                     const float* __restrict__ bias,
                     float* __restrict__ C)
{
    constexpr int K = 1024, N = 1024;
    __shared__ ushort As[128 * 64];
    __shared__ ushort Bs[64 * 64];

    const int tid  = threadIdx.x;
    const int wave = tid >> 6;
    const int lane = tid & 63;
    const int l16  = lane & 15;
    const int quad = lane >> 4;
    const int wm = wave & 1, wn = wave >> 1;

    const int bm = blockIdx.y * 128;
    const int bn = blockIdx.x * 64;

    const int srow = lane >> 3;
    const int lblk = (lane & 7) ^ srow;
    const ushort* Ag = A  + (size_t)(bm + wave * 32 + srow) * K + lblk * 8;
    const ushort* Bg = Bt + (size_t)(bn + wave * 16 + srow) * K + lblk * 8;
    ushort* Asl = As + wave * 32 * 64;
    ushort* Bsl = Bs + wave * 16 * 64;

    f32x4 acc[4][2];
    #pragma unroll
    for (int i = 0; i < 4; i++)
        #pragma unroll
        for (int j = 0; j < 2; j++) acc[i][j] = (f32x4){0.f, 0.f, 0.f, 0.f};

    for (int k0 = 0; k0 < K; k0 += 64) {
        __syncthreads();
        #pragma unroll
        for (int t = 0; t < 4; t++)
            async_copy16(Ag + (size_t)t * 8 * K + k0, Asl + t * 8 * 64);
        #pragma unroll
        for (int t = 0; t < 2; t++)
            async_copy16(Bg + (size_t)t * 8 * K + k0, Bsl + t * 8 * 64);
        __syncthreads();

        #pragma unroll
        for (int s = 0; s < 2; s++) {
            bf16x8 af[4], bfr[2];
            #pragma unroll
            for (int i = 0; i < 4; i++) {
                int m = wm * 64 + i * 16 + l16;
                af[i] = *(const bf16x8*)&As[m * 64 + (((s * 4 + quad) ^ (m & 7)) << 3)];
            }
            #pragma unroll
            for (int j = 0; j < 2; j++) {
                int n = wn * 32 + j * 16 + l16;
                bfr[j] = *(const bf16x8*)&Bs[n * 64 + (((s * 4 + quad) ^ (n & 7)) << 3)];
            }
            #pragma unroll
            for (int i = 0; i < 4; i++)
                #pragma unroll
                for (int j = 0; j < 2; j++)
                    acc[i][j] = __builtin_amdgcn_mfma_f32_16x16x32_bf16(af[i], bfr[j], acc[i][j], 0, 0, 0);
        }
    }

    #pragma unroll
    for (int j = 0; j < 2; j++) {
        int col = bn + wn * 32 + j * 16 + l16;
        float bv = bias[col];
        #pragma unroll
        for (int i = 0; i < 4; i++) {
            int row0 = bm + wm * 64 + i * 16 + quad * 4;
            #pragma unroll
            for (int r = 0; r < 4; r++)
                C[(size_t)(row0 + r) * N + col] = acc[i][j][r] + bv;
        }
    }
}

// ---------------------------------------------------------------------------
// Flash attention v7: ONE WAVE PER BLOCK, zero barriers. 64 threads, mg=4
// (64 q-rows), full 2048 keys (32 iters), grid B*NH*(SEQ/64) = 1024 blocks
// -> 4 independent waves/CU that drift out of phase and keep the LDS pipe
// busy (R9's __syncthreads phase-aligned all waves; no pipe exceeded ~52%).
// Staging stays coalesced global_load_lds into this wave's PRIVATE tile;
// vmcnt is per-wave so s_waitcnt vmcnt(0) is the only ordering needed.
// exp2 softmax (Q pre-scaled 0.125*log2e), no online max, l via ones-MFMA,
// Pi-packed trunc P, V pre-transposed by GEMM1. LDS 25.6 KB/block.
// ---------------------------------------------------------------------------
__global__ __launch_bounds__(64)
void attn_mfma_v7_kernel(const ushort* __restrict__ qkvb,
                         const ushort* __restrict__ vtg,
                         ushort* __restrict__ attn)
{
    // ushort layout: Ks[4096] | Vs[4096] @4096 | Ps @8192 (64 rows x stride 72)
    __shared__ __align__(16) ushort smem[12800];

    const int lane = threadIdx.x;
    const int l16  = lane & 15;
    const int quad = lane >> 4;

    const int qb = blockIdx.x & 31;    // 32 q-tiles of 64
    const int bh = blockIdx.x >> 5;
    const int h  = bh & (NH - 1);
    const int b  = bh >> 4;

    const int qbase = qb * 64;
    const int hoff  = h * 64;

    ushort* Ks = smem;
    ushort* Vs = smem + 4096;
    ushort* Ps = smem + 8192;

    // Q A-frags (pre-scaled by 0.125*log2e in GEMM1)
    bf16x8 a_q[4][2];
    #pragma unroll
    for (int mg = 0; mg < 4; mg++) {
        int qrow = b * SEQ + qbase + mg * 16 + l16;
        const ushort* qp = qkvb + (size_t)qrow * 3072 + hoff + quad * 8;
        a_q[mg][0] = *(const bf16x8*)qp;
        a_q[mg][1] = *(const bf16x8*)(qp + 32);
    }

    f32x4 o[4][4];
    f32x4 lacc[4];
    #pragma unroll
    for (int mg = 0; mg < 4; mg++) {
        lacc[mg] = (f32x4){0.f, 0.f, 0.f, 0.f};
        #pragma unroll
        for (int nt = 0; nt < 4; nt++) o[mg][nt] = (f32x4){0.f, 0.f, 0.f, 0.f};
    }

    bf16x8 b_ones;
    #pragma unroll
    for (int j = 0; j < 8; j++) b_ones[j] = (short)0x3f80;

    const ushort* kvb    = qkvb + (size_t)b * SEQ * 3072;
    const ushort* vtg_bh = vtg + (size_t)((b * NH + h) * 64) * SEQ;

    // staging: 8 insts K + 8 insts V per 64-key tile; XOR swizzle on global side
    const int srow8 = lane >> 3;
    const int gblk  = ((lane & 7) ^ srow8) << 3;
    const ushort* kg = kvb + (size_t)srow8 * 3072 + 1024 + hoff + gblk;
    const ushort* vg = vtg_bh + (size_t)srow8 * SEQ + gblk;

    for (int t = 0; t < 32; t++) {
        const int k0 = t * 64;
        // prior frag reads must be done before overwriting the tile
        asm volatile("s_waitcnt lgkmcnt(0)" ::: "memory");
        #pragma unroll
        for (int c = 0; c < 8; c++) {
            async_copy16(kg + (size_t)(k0 + c * 8) * 3072, Ks + c * 512);
            async_copy16(vg + (size_t)(c * 8) * SEQ + k0,  Vs + c * 512);
        }
        // per-wave vmcnt: our 16 loads (incl. LDS deposit) complete
        asm volatile("s_waitcnt vmcnt(0)" ::: "memory");

        // S = Q K^T (base-2 pre-scaled)
        f32x4 sc[4][4];
        #pragma unroll
        for (int nt = 0; nt < 4; nt++) {
            int key = nt * 16 + l16;
            bf16x8 bk0 = *(const bf16x8*)&Ks[key * 64 + ((quad ^ (key & 7)) << 3)];
            bf16x8 bk1 = *(const bf16x8*)&Ks[key * 64 + (((4 + quad) ^ (key & 7)) << 3)];
            #pragma unroll
            for (int mg = 0; mg < 4; mg++) {
                f32x4 a = (f32x4){0.f, 0.f, 0.f, 0.f};
                a = __builtin_amdgcn_mfma_f32_16x16x32_bf16(a_q[mg][0], bk0, a, 0, 0, 0);
                a = __builtin_amdgcn_mfma_f32_16x16x32_bf16(a_q[mg][1], bk1, a, 0, 0, 0);
                sc[mg][nt] = a;
            }
        }

        // P = exp2(S), trunc-packed b64 into Pi-slot order slot(key)=l16*4+nt
        #pragma unroll
        for (int mg = 0; mg < 4; mg++) {
            #pragma unroll
            for (int r = 0; r < 4; r++) {
                int q = mg * 16 + quad * 4 + r;
                uint2 pk2;
                pk2.x = pack_bf_trunc(fexp2(sc[mg][0][r]), fexp2(sc[mg][1][r]));
                pk2.y = pack_bf_trunc(fexp2(sc[mg][2][r]), fexp2(sc[mg][3][r]));
                *(uint2*)&Ps[q * 72 + l16 * 4] = pk2;
            }
        }

        // same-wave RAW through LDS
        asm volatile("s_waitcnt lgkmcnt(0)" ::: "memory");

        // O += P V (Pi-consistent), l += P @ ones
        #pragma unroll
        for (int mg = 0; mg < 4; mg++) {
            bf16x8 ap0 = *(const bf16x8*)&Ps[(mg * 16 + l16) * 72 + quad * 8];
            bf16x8 ap1 = *(const bf16x8*)&Ps[(mg * 16 + l16) * 72 + 32 + quad * 8];
            #pragma unroll
            for (int nt = 0; nt < 4; nt++) {
                int d = nt * 16 + l16;
                bf16x8 bv0 = *(const bf16x8*)&Vs[d * 64 + ((quad ^ (d & 7)) << 3)];
                bf16x8 bv1 = *(const bf16x8*)&Vs[d * 64 + (((4 + quad) ^ (d & 7)) << 3)];
                o[mg][nt] = __builtin_amdgcn_mfma_f32_16x16x32_bf16(ap0, bv0, o[mg][nt], 0, 0, 0);
                o[mg][nt] = __builtin_amdgcn_mfma_f32_16x16x32_bf16(ap1, bv1, o[mg][nt], 0, 0, 0);
            }
            lacc[mg] = __builtin_amdgcn_mfma_f32_16x16x32_bf16(ap0, b_ones, lacc[mg], 0, 0, 0);
            lacc[mg] = __builtin_amdgcn_mfma_f32_16x16x32_bf16(ap1, b_ones, lacc[mg], 0, 0, 0);
        }
    }

    // epilogue: normalize + store bf16 (no combine — full key range per wave)
    #pragma unroll
    for (int mg = 0; mg < 4; mg++) {
        #pragma unroll
        for (int r = 0; r < 4; r++) {
            float inv = 1.f / lacc[mg][r];
            int row = b * SEQ + qbase + mg * 16 + quad * 4 + r;
            size_t base = (size_t)row * HIDDEN + hoff + l16;
            #pragma unroll
            for (int nt = 0; nt < 4; nt++)
                attn[base + nt * 16] = f2bf(o[mg][nt][r] * inv);
        }
    }
}

// ---------------------------------------------------------------------------
// Fallback attention (no vtg workspace): barrier kernel staging K + Pi-V.
// ---------------------------------------------------------------------------
__global__ __launch_bounds__(512, 4)
void attn_mfma_fb_kernel(const ushort* __restrict__ qkvb,
                         ushort* __restrict__ attn)
{
    __shared__ __align__(16) ushort smem[34816];

    const int tid   = threadIdx.x;
    const int wave  = tid >> 6;
    const int wavel = wave & 3;
    const int kh    = wave >> 2;
    const int lane  = tid & 63;
    const int l16   = lane & 15;
    const int quad  = lane >> 4;

    const int qb = blockIdx.x & 15;
    const int bh = blockIdx.x >> 4;
    const int h  = bh & (NH - 1);
    const int b  = bh >> 4;

    const int qbase = qb * 128;
    const int hoff  = h * 64;

    ushort* KsH = smem + kh * 4096;
    ushort* VsH = smem + 8192 + kh * 4096;
    ushort* Psw = smem + 16384 + wave * 2304;

    bf16x8 a_q[2][2];
    #pragma unroll
    for (int mg = 0; mg < 2; mg++) {
        int qrow = b * SEQ + qbase + wavel * 32 + mg * 16 + l16;
        const ushort* qp = qkvb + (size_t)qrow * 3072 + hoff + quad * 8;
        a_q[mg][0] = *(const bf16x8*)qp;
        a_q[mg][1] = *(const bf16x8*)(qp + 32);
    }

    f32x4 o[2][4];
    f32x4 lacc[2];
    #pragma unroll
    for (int mg = 0; mg < 2; mg++) {
        lacc[mg] = (f32x4){0.f, 0.f, 0.f, 0.f};
        #pragma unroll
        for (int nt = 0; nt < 4; nt++) o[mg][nt] = (f32x4){0.f, 0.f, 0.f, 0.f};
    }

    bf16x8 b_ones;
    #pragma unroll
    for (int j = 0; j < 8; j++) b_ones[j] = (short)0x3f80;

    const ushort* kvb = qkvb + (size_t)b * SEQ * 3072;

    for (int t = 0; t < 16; t++) {
        const int k0 = t * 64;
        __syncthreads();
        {
            const int tl = tid & 255;
            #pragma unroll
            for (int i = 0; i < 2; i++) {
                int key = (tl >> 3) + 32 * i;
                int blk = tl & 7;
                const ushort* ksrc = kvb + (size_t)(kh * 1024 + k0 + key) * 3072 + 1024 + hoff + blk * 8;
                uint4 kv = *(const uint4*)ksrc;
                *(uint4*)&KsH[key * 64 + ((blk ^ (key & 7)) << 3)] = kv;
                uint4 vv = *(const uint4*)(ksrc + 1024);
                const ushort* vpp = (const ushort*)&vv;
                int pk_ = (key & 15) * 4 + (key >> 4);
                #pragma unroll
                for (int j = 0; j < 8; j++) {
                    int d = blk * 8 + j;
                    VsH[d * 64 + (((pk_ >> 3) ^ (d & 7)) << 3) + (pk_ & 7)] = vpp[j];
                }
            }
        }
        __syncthreads();

        f32x4 sc[2][4];
        #pragma unroll
        for (int nt = 0; nt < 4; nt++) {
            int key = nt * 16 + l16;
            bf16x8 bk0 = *(const bf16x8*)&KsH[key * 64 + ((quad ^ (key & 7)) << 3)];
            bf16x8 bk1 = *(const bf16x8*)&KsH[key * 64 + (((4 + quad) ^ (key & 7)) << 3)];
            #pragma unroll
            for (int mg = 0; mg < 2; mg++) {
                f32x4 a = (f32x4){0.f, 0.f, 0.f, 0.f};
                a = __builtin_amdgcn_mfma_f32_16x16x32_bf16(a_q[mg][0], bk0, a, 0, 0, 0);
                a = __builtin_amdgcn_mfma_f32_16x16x32_bf16(a_q[mg][1], bk1, a, 0, 0, 0);
                sc[mg][nt] = a;
            }
        }

        #pragma unroll
        for (int mg = 0; mg < 2; mg++) {
            #pragma unroll
            for (int r = 0; r < 4; r++) {
                int q = mg * 16 + quad * 4 + r;
                uint2 pk2;
                pk2.x = pack_bf_trunc(fexp2(sc[mg][0][r]), fexp2(sc[mg][1][r]));
                pk2.y = pack_bf_trunc(fexp2(sc[mg][2][r]), fexp2(sc[mg][3][r]));
                *(uint2*)&Psw[q * 72 + l16 * 4] = pk2;
            }
        }

        asm volatile("s_waitcnt lgkmcnt(0)" ::: "memory");
        bf16x8 a_p[2][2];
        #pragma unroll
        for (int mg = 0; mg < 2; mg++) {
            a_p[mg][0] = *(const bf16x8*)&Psw[(mg * 16 + l16) * 72 + quad * 8];
            a_p[mg][1] = *(const bf16x8*)&Psw[(mg * 16 + l16) * 72 + 32 + quad * 8];
        }

        #pragma unroll
        for (int nt = 0; nt < 4; nt++) {
            int d = nt * 16 + l16;
            bf16x8 bv0 = *(const bf16x8*)&VsH[d * 64 + ((quad ^ (d & 7)) << 3)];
            bf16x8 bv1 = *(const bf16x8*)&VsH[d * 64 + (((4 + quad) ^ (d & 7)) << 3)];
            #pragma unroll
            for (int mg = 0; mg < 2; mg++) {
                o[mg][nt] = __builtin_amdgcn_mfma_f32_16x16x32_bf16(a_p[mg][0], bv0, o[mg][nt], 0, 0, 0);
                o[mg][nt] = __builtin_amdgcn_mfma_f32_16x16x32_bf16(a_p[mg][1], bv1, o[mg][nt], 0, 0, 0);
            }
        }
        #pragma unroll
        for (int mg = 0; mg < 2; mg++) {
            lacc[mg] = __builtin_amdgcn_mfma_f32_16x16x32_bf16(a_p[mg][0], b_ones, lacc[mg], 0, 0, 0);
            lacc[mg] = __builtin_amdgcn_mfma_f32_16x16x32_bf16(a_p[mg][1], b_ones, lacc[mg], 0, 0, 0);
        }
    }

    __syncthreads();
    float* osc = (float*)smem;
    float* lsc = (float*)(smem + 16384);
    const int fo = wavel * 2048 + quad * 64 + l16 * 4;
    const int fl = wavel * 512 + quad * 64 + l16 * 4;
    if (kh == 1) {
        #pragma unroll
        for (int mg = 0; mg < 2; mg++) {
            #pragma unroll
            for (int nt = 0; nt < 4; nt++)
                *(f32x4*)&osc[fo + (mg * 4 + nt) * 256] = o[mg][nt];
            *(f32x4*)&lsc[fl + mg * 256] = lacc[mg];
        }
    }
    __syncthreads();
    if (kh == 0) {
        #pragma unroll
        for (int mg = 0; mg < 2; mg++) {
            #pragma unroll
            for (int nt = 0; nt < 4; nt++)
                o[mg][nt] += *(const f32x4*)&osc[fo + (mg * 4 + nt) * 256];
            lacc[mg] += *(const f32x4*)&lsc[fl + mg * 256];
        }
        #pragma unroll
        for (int mg = 0; mg < 2; mg++) {
            #pragma unroll
            for (int r = 0; r < 4; r++) {
                float inv = 1.f / lacc[mg][r];
                int row = b * SEQ + qbase + wavel * 32 + mg * 16 + quad * 4 + r;
                size_t base = (size_t)row * HIDDEN + hoff + l16;
                #pragma unroll
                for (int nt = 0; nt < 4; nt++)
                    attn[base + nt * 16] = f2bf(o[mg][nt][r] * inv);
            }
        }
    }
}

extern "C" void kernel_launch(void* const* d_in, const int* in_sizes, int n_in,
                              void* d_out, int out_size, void* d_ws, size_t ws_size,
                              hipStream_t stream) {
    const float* x    = (const float*)d_in[0];
    const float* Wqkv = (const float*)d_in[1];
    const float* bqkv = (const float*)d_in[2];
    const float* Wo   = (const float*)d_in[3];
    const float* bo   = (const float*)d_in[4];
    float* out = (float*)d_out;

    const int M = BATCH * SEQ;                   // 4096
    const size_t MB = 1024 * 1024;

    // workspace (48 MB):
    //   [0,24) qkvb | [24,32) attn (xb overlaps: prep/GEMM1 only)
    //   [32,38) Wt (prep/GEMM1) | [38,40) WoT (prep->GEMM3) | [40,48) vtg
    char* ws = (char*)d_ws;
    ushort* qkvb = (ushort*)ws;
    ushort* attn = (ushort*)(ws + 24 * MB);
    ushort* xb   = (ushort*)(ws + 24 * MB);
    ushort* Wt   = (ushort*)(ws + 32 * MB);
    ushort* WoT  = (ushort*)(ws + 38 * MB);
    ushort* vtg  = (ushort*)(ws + 40 * MB);
    const int use_vtg = (ws_size >= 48 * MB) ? 1 : 0;

    const float qscale = 0.125f * 1.44269504088896f;   // fold log2e -> exp2 softmax

    // 0) fused preps (x->bf16, Wqkv transpose, Wo transpose)
    prep_kernel<<<8192, 256, 0, stream>>>(x, Wqkv, Wo, xb, Wt, WoT);

    // 1) qkv = (x @ Wqkv + bqkv) -> bf16; V written transposed to vtg when able
    {
        dim3 grid((3 * HIDDEN) / 128, M / 128);
        gemm_mfma_bf16_kernel<<<grid, 256, 0, stream>>>(xb, Wt, bqkv, qkvb,
                                                        3 * HIDDEN, HIDDEN, qscale,
                                                        vtg, use_vtg);
    }

    // 2) flash attention -> attn bf16
    if (use_vtg) {
        attn_mfma_v7_kernel<<<BATCH * NH * (SEQ / 64), 64, 0, stream>>>(
            qkvb, vtg, attn);
    } else {
        attn_mfma_fb_kernel<<<BATCH * NH * (SEQ / 128), 512, 0, stream>>>(
            qkvb, attn);
    }

    // 3) out = attn @ Wo + bo (single-pass bf16 MFMA)
    {
        dim3 grid(HIDDEN / 64, M / 128);
        gemm_out_kernel<<<grid, 256, 0, stream>>>(attn, WoT, bo, out);
    }
}